// Round 7
// baseline (574.628 us; speedup 1.0000x reference)
//
#include <hip/hip_runtime.h>
#include <hip/hip_bf16.h>

// GAT 2-layer, N=50000, E=800000, D=128, H=2, F=128, C=H*F=256.
// Round 7: fixed column-sharding.
//  - featb stored shard-major [8][N][32]: one aligned 64B line per edge-shard.
//  - xprep pre-pass computes exp-scores once per edge (kills the 8x el-gather
//    replication that sank round 6), CSR-ordered -> shards read sequentially.
//  - aggregate: wave=(node,shard), 4 edge slots x 16 lanes x 4B; slot butterfly
//    shfl_xor(16/32); head partner via shfl_xor(8). shard=blockIdx&7 -> XCD.
// GEMM (bf16x3 MFMA) / CSR build unchanged except featb store indexing.

#define NEG_SLOPE 0.2f

typedef __attribute__((ext_vector_type(8))) short bf16x8_t;
typedef __attribute__((ext_vector_type(4))) float f32x4_t;

__device__ __forceinline__ unsigned short f2bf(float f) {
  union { float f; unsigned int u; } v; v.f = f;
  unsigned int r = v.u + 0x7FFFu + ((v.u >> 16) & 1u);
  return (unsigned short)(r >> 16);
}
__device__ __forceinline__ float bfbits(unsigned int hi16) {
  union { unsigned int u; float f; } v; v.u = hi16;
  return v.f;
}

// ---------------- CSR build ----------------

__global__ void hist_kernel(const int* __restrict__ dst, int* __restrict__ counts, int n_edges) {
  int e = blockIdx.x * blockDim.x + threadIdx.x;
  if (e < n_edges) atomicAdd(&counts[dst[e]], 1);
}

__global__ __launch_bounds__(256) void scan1_kernel(const int* __restrict__ counts,
                                                    int* __restrict__ blocksum, int n) {
  __shared__ int wsum[4];
  int t = threadIdx.x;
  int i0 = blockIdx.x * 1024 + t * 4;
  int s = 0;
  if (i0 + 3 < n) {
    int4 c = *(const int4*)&counts[i0];
    s = c.x + c.y + c.z + c.w;
  } else {
    #pragma unroll
    for (int i = 0; i < 4; ++i) if (i0 + i < n) s += counts[i0 + i];
  }
  int v = s;
  #pragma unroll
  for (int off = 1; off < 64; off <<= 1) v += __shfl_xor(v, off);
  if ((t & 63) == 0) wsum[t >> 6] = v;
  __syncthreads();
  if (t == 0) blocksum[blockIdx.x] = wsum[0] + wsum[1] + wsum[2] + wsum[3];
}

__global__ __launch_bounds__(256) void scan2_kernel(const int* __restrict__ blocksum,
                                                    int* __restrict__ blockoff, int nb,
                                                    int* __restrict__ offsets, int n) {
  __shared__ int wsum[4];
  int t = threadIdx.x;
  int v = (t < nb) ? blocksum[t] : 0;
  int lane = t & 63, wid = t >> 6;
  int inc = v;
  #pragma unroll
  for (int off = 1; off < 64; off <<= 1) {
    int u = __shfl_up(inc, off);
    if (lane >= off) inc += u;
  }
  if (lane == 63) wsum[wid] = inc;
  __syncthreads();
  int wbase = 0;
  for (int w = 0; w < wid; ++w) wbase += wsum[w];
  if (t < nb) blockoff[t] = wbase + inc - v;   // exclusive
  if (t == 255) offsets[n] = wbase + inc;      // grand total
}

__global__ __launch_bounds__(256) void scan3_kernel(const int* __restrict__ counts,
                                                    const int* __restrict__ blockoff,
                                                    int* __restrict__ offsets,
                                                    int* __restrict__ cursor, int n) {
  __shared__ int wsum[4];
  int t = threadIdx.x;
  int i0 = blockIdx.x * 1024 + t * 4;
  int c0 = 0, c1 = 0, c2 = 0, c3 = 0;
  if (i0 + 3 < n) {
    int4 c = *(const int4*)&counts[i0];
    c0 = c.x; c1 = c.y; c2 = c.z; c3 = c.w;
  } else {
    if (i0 + 0 < n) c0 = counts[i0 + 0];
    if (i0 + 1 < n) c1 = counts[i0 + 1];
    if (i0 + 2 < n) c2 = counts[i0 + 2];
    if (i0 + 3 < n) c3 = counts[i0 + 3];
  }
  int s = c0 + c1 + c2 + c3;
  int lane = t & 63, wid = t >> 6;
  int inc = s;
  #pragma unroll
  for (int off = 1; off < 64; off <<= 1) {
    int u = __shfl_up(inc, off);
    if (lane >= off) inc += u;
  }
  if (lane == 63) wsum[wid] = inc;
  __syncthreads();
  int wbase = 0;
  for (int w = 0; w < wid; ++w) wbase += wsum[w];
  int o0 = blockoff[blockIdx.x] + wbase + (inc - s);
  int o1 = o0 + c0, o2 = o1 + c1, o3 = o2 + c2;
  if (i0 + 3 < n) {
    *(int4*)&offsets[i0] = make_int4(o0, o1, o2, o3);
    *(int4*)&cursor[i0]  = make_int4(o0, o1, o2, o3);
  } else {
    if (i0 + 0 < n) { offsets[i0 + 0] = o0; cursor[i0 + 0] = o0; }
    if (i0 + 1 < n) { offsets[i0 + 1] = o1; cursor[i0 + 1] = o1; }
    if (i0 + 2 < n) { offsets[i0 + 2] = o2; cursor[i0 + 2] = o2; }
    if (i0 + 3 < n) { offsets[i0 + 3] = o3; cursor[i0 + 3] = o3; }
  }
}

// scatter: writes src id directly into CSR slot
__global__ void scatter_kernel(const int* __restrict__ src, const int* __restrict__ dst,
                               int* __restrict__ cursor, int* __restrict__ srcp, int n_edges) {
  int e = blockIdx.x * blockDim.x + threadIdx.x;
  if (e < n_edges) {
    int p = atomicAdd(&cursor[dst[e]], 1);
    srcp[p] = src[e];
  }
}

// ---------------- W pack: fp32 -> bf16 hi/lo in B-fragment order ----------------

__global__ __launch_bounds__(256) void wpack_kernel(const float* __restrict__ Ws,
                                                    unsigned short* __restrict__ Whi,
                                                    unsigned short* __restrict__ Wlo) {
  int t = blockIdx.x * 256 + threadIdx.x;   // 8192 threads: 2 lay x 4 s x 16 ct x 64 lane
  int lane = t & 63;
  int ct = (t >> 6) & 15;
  int s = (t >> 10) & 3;
  int lay = t >> 12;
  int col = ct * 16 + (lane & 15);
  int kbase = s * 32 + (lane >> 4) * 8;
  size_t obase = (size_t)t * 8;
  #pragma unroll
  for (int j = 0; j < 8; ++j) {
    float w = Ws[(size_t)lay * 32768 + (size_t)(kbase + j) * 256 + col];
    unsigned short hb = f2bf(w);
    float rem = w - bfbits((unsigned int)hb << 16);
    Whi[obase + j] = hb;
    Wlo[obase + j] = f2bf(rem);
  }
}

// ---------------- MFMA GEMM: feat = h @ W (bf16x3), fused el/er ----------------
// featb written shard-major: featb[shard][node][32], shard = head0 cols
// [16s,16s+16) at j=0..15, head1 cols [128+16s,128+16s+16) at j=16..31.

__global__ __launch_bounds__(256) void gemm_feat_kernel(
    const float* __restrict__ hin,
    const unsigned short* __restrict__ Whi, const unsigned short* __restrict__ Wlo,
    const float* __restrict__ al, const float* __restrict__ ar,
    unsigned short* __restrict__ featb, float* __restrict__ el, float* __restrict__ er,
    int n_nodes)
{
  const int tid = threadIdx.x;
  const int w = tid >> 6;
  const int lane = tid & 63;
  const int lrow = lane & 15;
  const int g = lane >> 4;
  const int node0 = blockIdx.x * 64 + w * 16;

  f32x4_t acc[16];
  #pragma unroll
  for (int i = 0; i < 16; ++i) acc[i] = (f32x4_t){0.f, 0.f, 0.f, 0.f};

  int arow = node0 + lrow;
  int arow_c = (arow < n_nodes) ? arow : (n_nodes - 1);
  const float* aptr = hin + (size_t)arow_c * 128 + g * 8;

  for (int s = 0; s < 4; ++s) {
    float4 f0 = *(const float4*)(aptr + s * 32);
    float4 f1 = *(const float4*)(aptr + s * 32 + 4);
    float fv[8] = {f0.x, f0.y, f0.z, f0.w, f1.x, f1.y, f1.z, f1.w};
    bf16x8_t ahi, alo;
    #pragma unroll
    for (int j = 0; j < 8; ++j) {
      unsigned short hb = f2bf(fv[j]);
      float rem = fv[j] - bfbits((unsigned int)hb << 16);
      ahi[j] = (short)hb;
      alo[j] = (short)f2bf(rem);
    }
    const unsigned short* bh_p = Whi + ((size_t)(s * 16) * 64 + lane) * 8;
    const unsigned short* bl_p = Wlo + ((size_t)(s * 16) * 64 + lane) * 8;
    #pragma unroll
    for (int ct = 0; ct < 16; ++ct) {
      bf16x8_t bh = *(const bf16x8_t*)(bh_p + (size_t)ct * 512);
      bf16x8_t bl = *(const bf16x8_t*)(bl_p + (size_t)ct * 512);
      acc[ct] = __builtin_amdgcn_mfma_f32_16x16x32_bf16(ahi, bh, acc[ct], 0, 0, 0);
      acc[ct] = __builtin_amdgcn_mfma_f32_16x16x32_bf16(alo, bh, acc[ct], 0, 0, 0);
      acc[ct] = __builtin_amdgcn_mfma_f32_16x16x32_bf16(ahi, bl, acc[ct], 0, 0, 0);
    }
  }

  float alc[16], arc[16];
  #pragma unroll
  for (int ct = 0; ct < 16; ++ct) {
    alc[ct] = al[ct * 16 + lrow];
    arc[ct] = ar[ct * 16 + lrow];
  }
  #pragma unroll
  for (int r = 0; r < 4; ++r) {
    int orow = node0 + g * 4 + r;
    bool ok = orow < n_nodes;
    float pl0 = 0.f, pl1 = 0.f, pr0 = 0.f, pr1 = 0.f;
    #pragma unroll
    for (int ct = 0; ct < 16; ++ct) {
      float v = acc[ct][r];
      if (ct < 8) { pl0 += v * alc[ct]; pr0 += v * arc[ct]; }
      else        { pl1 += v * alc[ct]; pr1 += v * arc[ct]; }
      if (ok) {
        size_t shard = (ct < 8) ? (size_t)ct : (size_t)(ct - 8);
        int jj = (ct < 8) ? lrow : (16 + lrow);
        featb[(shard * (size_t)n_nodes + (size_t)orow) * 32 + jj] = f2bf(v);
      }
    }
    #pragma unroll
    for (int off = 1; off < 16; off <<= 1) {
      pl0 += __shfl_xor(pl0, off);
      pl1 += __shfl_xor(pl1, off);
      pr0 += __shfl_xor(pr0, off);
      pr1 += __shfl_xor(pr1, off);
    }
    if (lrow == 0 && ok) {
      *(float2*)&el[(size_t)orow * 2] = make_float2(pl0, pl1);
      *(float2*)&er[(size_t)orow * 2] = make_float2(pr0, pr1);
    }
  }
}

// ---------------- xp pre-pass: per-edge exp scores, CSR order ----------------
// One wave per node: er loaded once; el gathered ONCE per edge (not 8x).

__global__ __launch_bounds__(256) void xprep_kernel(
    const float* __restrict__ el, const float* __restrict__ er,
    const int* __restrict__ srcp, const int* __restrict__ offsets,
    float2* __restrict__ xp, int n_nodes)
{
  int node = blockIdx.x * 4 + (threadIdx.x >> 6);
  int lane = threadIdx.x & 63;
  if (node >= n_nodes) return;
  int beg = offsets[node];
  int end = offsets[node + 1];
  float2 ern = *(const float2*)&er[(size_t)node * 2];
  for (int j = beg + lane; j < end; j += 64) {
    int s = srcp[j];
    float2 l = *(const float2*)&el[(size_t)s * 2];
    float e0 = l.x + ern.x;
    float e1 = l.y + ern.y;
    e0 = fminf((e0 >= 0.f) ? e0 : NEG_SLOPE * e0, 60.f);
    e1 = fminf((e1 >= 0.f) ? e1 : NEG_SLOPE * e1, 60.f);
    xp[j] = make_float2(__expf(e0), __expf(e1));
  }
}

// ---------------- sharded aggregation ----------------
// Wave = (node, shard=blockIdx&7). 4 edge slots x 16 lanes; lane c reads 4B
// (cols 2c,2c+1 of the 32-col slice; c<8 head0, c>=8 head1). One 64B line per
// edge per shard, slice (3.2MB) resident in the shard's XCD L2.

__global__ __launch_bounds__(256) void aggregate_kernel(
    const unsigned short* __restrict__ featb,   // [8][N][32]
    const float2* __restrict__ xp,
    const int* __restrict__ srcp, const int* __restrict__ offsets,
    const float* __restrict__ b,
    float* __restrict__ out, float* __restrict__ hnext, int n_nodes)
{
  const int shard = blockIdx.x & 7;
  const int node = (blockIdx.x >> 3) * 4 + (threadIdx.x >> 6);
  const int lane = threadIdx.x & 63;
  if (node >= n_nodes) return;
  const int slot = lane >> 4;
  const int c = lane & 15;

  const int beg = offsets[node];
  const int end = offsets[node + 1];
  const unsigned short* slice = featb + (size_t)shard * n_nodes * 32;

  float ax = 0.f, ay = 0.f, den = 0.f;
  for (int j = beg + slot; j < end; j += 4) {
    int s = srcp[j];
    float2 x2 = xp[j];
    unsigned int q = *(const unsigned int*)&slice[(size_t)s * 32 + c * 2];
    float x = (c < 8) ? x2.x : x2.y;
    den += x;
    ax = fmaf(x, bfbits(q << 16), ax);
    ay = fmaf(x, bfbits(q & 0xFFFF0000u), ay);
  }
  // merge 4 slot partials (c preserved)
  ax += __shfl_xor(ax, 16); ax += __shfl_xor(ax, 32);
  ay += __shfl_xor(ay, 16); ay += __shfl_xor(ay, 32);
  den += __shfl_xor(den, 16); den += __shfl_xor(den, 32);

  const int col = (c < 8) ? (shard * 16 + 2 * c) : (128 + shard * 16 + 2 * (c - 8));
  float2 b2 = *(const float2*)&b[col];
  float2 o;
  if (end > beg) {
    float inv = 1.0f / den;
    o.x = fmaf(ax, inv, b2.x);
    o.y = fmaf(ay, inv, b2.y);
  } else {
    o = b2;
  }
  // head partner: lane c^8 holds the other head's matching 2 cols
  float px = __shfl_xor(o.x, 8);
  float py = __shfl_xor(o.y, 8);

  if (slot == 0) {
    if (out) *(float2*)&out[(size_t)node * 256 + col] = o;
    if (hnext && c < 8) {
      float2 hn = make_float2((o.x + px) * 0.5f, (o.y + py) * 0.5f);
      *(float2*)&hnext[(size_t)node * 128 + shard * 16 + 2 * c] = hn;
    }
  }
}

// ---------------- launch ----------------

extern "C" void kernel_launch(void* const* d_in, const int* in_sizes, int n_in,
                              void* d_out, int out_size, void* d_ws, size_t ws_size,
                              hipStream_t stream) {
  const float* x   = (const float*)d_in[0];
  const float* Ws  = (const float*)d_in[1];
  const float* als = (const float*)d_in[2];
  const float* ars = (const float*)d_in[3];
  const float* bs  = (const float*)d_in[4];
  const int*   src = (const int*)d_in[5];
  const int*   dst = (const int*)d_in[6];
  const int N = in_sizes[0] / 128;   // 50000
  const int E = in_sizes[5];         // 800000
  float* out = (float*)d_out;

  char* ws = (char*)d_ws;
  auto alloc = [&](size_t bytes) {
    char* p = ws;
    ws += (bytes + 255) & ~(size_t)255;
    return p;
  };
  unsigned short* featb = (unsigned short*)alloc((size_t)N * 256 * 2);  // [8][N][32]
  float* hbuf    = (float*)alloc((size_t)N * 128 * 4);
  float2* xp     = (float2*)alloc((size_t)E * 8);
  int*   srcp    = (int*)alloc((size_t)E * 4);
  int*   offsets = (int*)alloc((size_t)(N + 1) * 4);
  int*   cursor  = (int*)alloc((size_t)N * 4);
  int*   counts  = (int*)alloc((size_t)N * 4);
  float* el      = (float*)alloc((size_t)N * 2 * 4);
  float* er      = (float*)alloc((size_t)N * 2 * 4);
  int*   blocksum = (int*)alloc((size_t)256 * 4);
  int*   blockoff = (int*)alloc((size_t)256 * 4);
  unsigned short* Whi = (unsigned short*)alloc((size_t)65536 * 2);
  unsigned short* Wlo = (unsigned short*)alloc((size_t)65536 * 2);

  const int nb = (N + 1023) / 1024;  // 49

  // CSR by dst (dst invariant across layers: build once)
  hipMemsetAsync(counts, 0, (size_t)N * 4, stream);
  hist_kernel<<<dim3((E + 255) / 256), dim3(256), 0, stream>>>(dst, counts, E);
  scan1_kernel<<<dim3(nb), dim3(256), 0, stream>>>(counts, blocksum, N);
  scan2_kernel<<<dim3(1), dim3(256), 0, stream>>>(blocksum, blockoff, nb, offsets, N);
  scan3_kernel<<<dim3(nb), dim3(256), 0, stream>>>(counts, blockoff, offsets, cursor, N);
  scatter_kernel<<<dim3((E + 255) / 256), dim3(256), 0, stream>>>(src, dst, cursor, srcp, E);

  // pack W (both layers) into MFMA B-fragment order, bf16 hi/lo
  wpack_kernel<<<dim3(32), dim3(256), 0, stream>>>(Ws, Whi, Wlo);

  const int ngrp = (N + 3) / 4;     // 4 nodes per block (one per wave)
  for (int l = 0; l < 2; ++l) {
    const float* hin = (l == 0) ? x : hbuf;
    const float* al  = als + (size_t)l * 256;
    const float* ar  = ars + (size_t)l * 256;
    const float* b   = bs  + (size_t)l * 256;
    gemm_feat_kernel<<<dim3((N + 63) / 64), dim3(256), 0, stream>>>(
        hin, Whi + (size_t)l * 32768, Wlo + (size_t)l * 32768,
        al, ar, featb, el, er, N);
    xprep_kernel<<<dim3(ngrp), dim3(256), 0, stream>>>(el, er, srcp, offsets, xp, N);
    aggregate_kernel<<<dim3(ngrp * 8), dim3(256), 0, stream>>>(
        featb, xp, srcp, offsets, b,
        (l == 1) ? out : nullptr,
        (l == 0) ? hbuf : nullptr, N);
  }
}

// Round 8
// 281.201 us; speedup vs baseline: 2.0435x; 2.0435x over previous
//
#include <hip/hip_runtime.h>
#include <hip/hip_bf16.h>

// GAT 2-layer, N=50000, E=800000, D=128, H=2, F=128, C=H*F=256.
// Round 8: revert aggregate to round-5 form (sharding was a regression:
// 8x wave count + replicated index streams made it latency-bound).
// GEMM: LDS-stage Whi/Wlo per 32-K chunk (32KB) once per block -> cuts the
// 4x per-wave B re-load (~400MB/layer L2 traffic) to ~100MB/layer.

#define NEG_SLOPE 0.2f

typedef __attribute__((ext_vector_type(8))) short bf16x8_t;
typedef __attribute__((ext_vector_type(4))) float f32x4_t;

__device__ __forceinline__ unsigned short f2bf(float f) {
  union { float f; unsigned int u; } v; v.f = f;
  unsigned int r = v.u + 0x7FFFu + ((v.u >> 16) & 1u);
  return (unsigned short)(r >> 16);
}
__device__ __forceinline__ float bfbits(unsigned int hi16) {
  union { unsigned int u; float f; } v; v.u = hi16;
  return v.f;
}

// ---------------- CSR build ----------------

__global__ void hist_kernel(const int* __restrict__ dst, int* __restrict__ counts, int n_edges) {
  int e = blockIdx.x * blockDim.x + threadIdx.x;
  if (e < n_edges) atomicAdd(&counts[dst[e]], 1);
}

__global__ __launch_bounds__(256) void scan1_kernel(const int* __restrict__ counts,
                                                    int* __restrict__ blocksum, int n) {
  __shared__ int wsum[4];
  int t = threadIdx.x;
  int i0 = blockIdx.x * 1024 + t * 4;
  int s = 0;
  if (i0 + 3 < n) {
    int4 c = *(const int4*)&counts[i0];
    s = c.x + c.y + c.z + c.w;
  } else {
    #pragma unroll
    for (int i = 0; i < 4; ++i) if (i0 + i < n) s += counts[i0 + i];
  }
  int v = s;
  #pragma unroll
  for (int off = 1; off < 64; off <<= 1) v += __shfl_xor(v, off);
  if ((t & 63) == 0) wsum[t >> 6] = v;
  __syncthreads();
  if (t == 0) blocksum[blockIdx.x] = wsum[0] + wsum[1] + wsum[2] + wsum[3];
}

__global__ __launch_bounds__(256) void scan2_kernel(const int* __restrict__ blocksum,
                                                    int* __restrict__ blockoff, int nb,
                                                    int* __restrict__ offsets, int n) {
  __shared__ int wsum[4];
  int t = threadIdx.x;
  int v = (t < nb) ? blocksum[t] : 0;
  int lane = t & 63, wid = t >> 6;
  int inc = v;
  #pragma unroll
  for (int off = 1; off < 64; off <<= 1) {
    int u = __shfl_up(inc, off);
    if (lane >= off) inc += u;
  }
  if (lane == 63) wsum[wid] = inc;
  __syncthreads();
  int wbase = 0;
  for (int w = 0; w < wid; ++w) wbase += wsum[w];
  if (t < nb) blockoff[t] = wbase + inc - v;   // exclusive
  if (t == 255) offsets[n] = wbase + inc;      // grand total
}

__global__ __launch_bounds__(256) void scan3_kernel(const int* __restrict__ counts,
                                                    const int* __restrict__ blockoff,
                                                    int* __restrict__ offsets,
                                                    int* __restrict__ cursor, int n) {
  __shared__ int wsum[4];
  int t = threadIdx.x;
  int i0 = blockIdx.x * 1024 + t * 4;
  int c0 = 0, c1 = 0, c2 = 0, c3 = 0;
  if (i0 + 3 < n) {
    int4 c = *(const int4*)&counts[i0];
    c0 = c.x; c1 = c.y; c2 = c.z; c3 = c.w;
  } else {
    if (i0 + 0 < n) c0 = counts[i0 + 0];
    if (i0 + 1 < n) c1 = counts[i0 + 1];
    if (i0 + 2 < n) c2 = counts[i0 + 2];
    if (i0 + 3 < n) c3 = counts[i0 + 3];
  }
  int s = c0 + c1 + c2 + c3;
  int lane = t & 63, wid = t >> 6;
  int inc = s;
  #pragma unroll
  for (int off = 1; off < 64; off <<= 1) {
    int u = __shfl_up(inc, off);
    if (lane >= off) inc += u;
  }
  if (lane == 63) wsum[wid] = inc;
  __syncthreads();
  int wbase = 0;
  for (int w = 0; w < wid; ++w) wbase += wsum[w];
  int o0 = blockoff[blockIdx.x] + wbase + (inc - s);
  int o1 = o0 + c0, o2 = o1 + c1, o3 = o2 + c2;
  if (i0 + 3 < n) {
    *(int4*)&offsets[i0] = make_int4(o0, o1, o2, o3);
    *(int4*)&cursor[i0]  = make_int4(o0, o1, o2, o3);
  } else {
    if (i0 + 0 < n) { offsets[i0 + 0] = o0; cursor[i0 + 0] = o0; }
    if (i0 + 1 < n) { offsets[i0 + 1] = o1; cursor[i0 + 1] = o1; }
    if (i0 + 2 < n) { offsets[i0 + 2] = o2; cursor[i0 + 2] = o2; }
    if (i0 + 3 < n) { offsets[i0 + 3] = o3; cursor[i0 + 3] = o3; }
  }
}

// scatter: writes src id directly into CSR slot
__global__ void scatter_kernel(const int* __restrict__ src, const int* __restrict__ dst,
                               int* __restrict__ cursor, int* __restrict__ srcp, int n_edges) {
  int e = blockIdx.x * blockDim.x + threadIdx.x;
  if (e < n_edges) {
    int p = atomicAdd(&cursor[dst[e]], 1);
    srcp[p] = src[e];
  }
}

// ---------------- W pack: fp32 -> bf16 hi/lo in B-fragment order ----------------

__global__ __launch_bounds__(256) void wpack_kernel(const float* __restrict__ Ws,
                                                    unsigned short* __restrict__ Whi,
                                                    unsigned short* __restrict__ Wlo) {
  int t = blockIdx.x * 256 + threadIdx.x;   // 8192 threads: 2 lay x 4 s x 16 ct x 64 lane
  int lane = t & 63;
  int ct = (t >> 6) & 15;
  int s = (t >> 10) & 3;
  int lay = t >> 12;
  int col = ct * 16 + (lane & 15);
  int kbase = s * 32 + (lane >> 4) * 8;
  size_t obase = (size_t)t * 8;
  #pragma unroll
  for (int j = 0; j < 8; ++j) {
    float w = Ws[(size_t)lay * 32768 + (size_t)(kbase + j) * 256 + col];
    unsigned short hb = f2bf(w);
    float rem = w - bfbits((unsigned int)hb << 16);
    Whi[obase + j] = hb;
    Wlo[obase + j] = f2bf(rem);
  }
}

// ---------------- MFMA GEMM: feat = h @ W (bf16x3), fused el/er ----------------
// Block 256 thr = 4 waves; tile 64 nodes x 256 cols. Whi/Wlo staged in LDS per
// 32-K chunk (16KB hi + 16KB lo), shared by all 4 waves (4x fewer B loads).
// A frag: row=lane&15, k=(lane>>4)*8+j. C/D: col=lane&15, row=(lane>>4)*4+reg.

__global__ __launch_bounds__(256) void gemm_feat_kernel(
    const float* __restrict__ hin,
    const unsigned short* __restrict__ Whi, const unsigned short* __restrict__ Wlo,
    const float* __restrict__ al, const float* __restrict__ ar,
    unsigned short* __restrict__ featb, float* __restrict__ el, float* __restrict__ er,
    int n_nodes)
{
  __shared__ unsigned short lds_bh[8192];   // 16 ct x 64 lane x 8
  __shared__ unsigned short lds_bl[8192];
  const int tid = threadIdx.x;
  const int w = tid >> 6;
  const int lane = tid & 63;
  const int lrow = lane & 15;
  const int g = lane >> 4;
  const int node0 = blockIdx.x * 64 + w * 16;

  f32x4_t acc[16];
  #pragma unroll
  for (int i = 0; i < 16; ++i) acc[i] = (f32x4_t){0.f, 0.f, 0.f, 0.f};

  int arow = node0 + lrow;
  int arow_c = (arow < n_nodes) ? arow : (n_nodes - 1);
  const float* aptr = hin + (size_t)arow_c * 128 + g * 8;

  for (int s = 0; s < 4; ++s) {
    // A chunk load + split (independent of LDS, issued before barrier)
    float4 f0 = *(const float4*)(aptr + s * 32);
    float4 f1 = *(const float4*)(aptr + s * 32 + 4);
    float fv[8] = {f0.x, f0.y, f0.z, f0.w, f1.x, f1.y, f1.z, f1.w};
    bf16x8_t ahi, alo;
    #pragma unroll
    for (int j = 0; j < 8; ++j) {
      unsigned short hb = f2bf(fv[j]);
      float rem = fv[j] - bfbits((unsigned int)hb << 16);
      ahi[j] = (short)hb;
      alo[j] = (short)f2bf(rem);
    }
    __syncthreads();   // previous chunk fully consumed
    const uint4* gh = (const uint4*)(Whi + (size_t)s * 8192);
    const uint4* gl = (const uint4*)(Wlo + (size_t)s * 8192);
    uint4* lh = (uint4*)lds_bh;
    uint4* ll = (uint4*)lds_bl;
    #pragma unroll
    for (int r = 0; r < 4; ++r) {
      lh[tid + 256 * r] = gh[tid + 256 * r];
      ll[tid + 256 * r] = gl[tid + 256 * r];
    }
    __syncthreads();
    #pragma unroll
    for (int ct = 0; ct < 16; ++ct) {
      bf16x8_t bh = *(const bf16x8_t*)&lds_bh[(ct * 64 + lane) * 8];
      bf16x8_t bl = *(const bf16x8_t*)&lds_bl[(ct * 64 + lane) * 8];
      acc[ct] = __builtin_amdgcn_mfma_f32_16x16x32_bf16(ahi, bh, acc[ct], 0, 0, 0);
      acc[ct] = __builtin_amdgcn_mfma_f32_16x16x32_bf16(alo, bh, acc[ct], 0, 0, 0);
      acc[ct] = __builtin_amdgcn_mfma_f32_16x16x32_bf16(ahi, bl, acc[ct], 0, 0, 0);
    }
  }

  float alc[16], arc[16];
  #pragma unroll
  for (int ct = 0; ct < 16; ++ct) {
    alc[ct] = al[ct * 16 + lrow];
    arc[ct] = ar[ct * 16 + lrow];
  }
  #pragma unroll
  for (int r = 0; r < 4; ++r) {
    int orow = node0 + g * 4 + r;
    bool ok = orow < n_nodes;
    float pl0 = 0.f, pl1 = 0.f, pr0 = 0.f, pr1 = 0.f;
    #pragma unroll
    for (int ct = 0; ct < 16; ++ct) {
      float v = acc[ct][r];
      if (ct < 8) { pl0 += v * alc[ct]; pr0 += v * arc[ct]; }
      else        { pl1 += v * alc[ct]; pr1 += v * arc[ct]; }
      if (ok) featb[(size_t)orow * 256 + ct * 16 + lrow] = f2bf(v);
    }
    #pragma unroll
    for (int off = 1; off < 16; off <<= 1) {
      pl0 += __shfl_xor(pl0, off);
      pl1 += __shfl_xor(pl1, off);
      pr0 += __shfl_xor(pr0, off);
      pr1 += __shfl_xor(pr1, off);
    }
    if (lrow == 0 && ok) {
      *(float2*)&el[(size_t)orow * 2] = make_float2(pl0, pl1);
      *(float2*)&er[(size_t)orow * 2] = make_float2(pr0, pr1);
    }
  }
}

// ---------------- fused score + aggregation (round-5 form) ----------------
// Per wave: one node. e = leaky(el[s] + er[node]) per head, x = exp(min(e,60));
// den per-lane (identical within half-wave). col = lane*4+i; lanes 0-31 head 0.

__global__ __launch_bounds__(256) void aggregate_kernel(
    const unsigned short* __restrict__ featb,
    const float* __restrict__ el, const float* __restrict__ er,
    const int* __restrict__ srcp, const int* __restrict__ offsets,
    const float* __restrict__ b,
    float* __restrict__ out, float* __restrict__ hnext, int n_nodes)
{
  int node = blockIdx.x * 4 + (threadIdx.x >> 6);
  int lane = threadIdx.x & 63;
  if (node >= n_nodes) return;
  int beg = offsets[node];
  int end = offsets[node + 1];

  float2 ern = *(const float2*)&er[(size_t)node * 2];
  const bool h0 = (lane < 32);
  const float er_m = h0 ? ern.x : ern.y;

  float4 acc = make_float4(0.f, 0.f, 0.f, 0.f);
  float den = 0.f;

  int j = beg;
  for (; j + 4 <= end; j += 4) {
    int s0 = srcp[j], s1 = srcp[j + 1], s2 = srcp[j + 2], s3 = srcp[j + 3];
    float2 l0 = *(const float2*)&el[(size_t)s0 * 2];
    float2 l1 = *(const float2*)&el[(size_t)s1 * 2];
    float2 l2 = *(const float2*)&el[(size_t)s2 * 2];
    float2 l3 = *(const float2*)&el[(size_t)s3 * 2];
    uint2 q0 = *(const uint2*)&featb[(size_t)s0 * 256 + lane * 4];
    uint2 q1 = *(const uint2*)&featb[(size_t)s1 * 256 + lane * 4];
    uint2 q2 = *(const uint2*)&featb[(size_t)s2 * 256 + lane * 4];
    uint2 q3 = *(const uint2*)&featb[(size_t)s3 * 256 + lane * 4];
    float e0 = (h0 ? l0.x : l0.y) + er_m;
    float e1 = (h0 ? l1.x : l1.y) + er_m;
    float e2 = (h0 ? l2.x : l2.y) + er_m;
    float e3 = (h0 ? l3.x : l3.y) + er_m;
    e0 = fminf((e0 >= 0.f) ? e0 : NEG_SLOPE * e0, 60.f);
    e1 = fminf((e1 >= 0.f) ? e1 : NEG_SLOPE * e1, 60.f);
    e2 = fminf((e2 >= 0.f) ? e2 : NEG_SLOPE * e2, 60.f);
    e3 = fminf((e3 >= 0.f) ? e3 : NEG_SLOPE * e3, 60.f);
    float x0 = __expf(e0), x1 = __expf(e1), x2 = __expf(e2), x3 = __expf(e3);
    den += (x0 + x1) + (x2 + x3);
    acc.x = fmaf(x0, bfbits(q0.x << 16), acc.x);
    acc.y = fmaf(x0, bfbits(q0.x & 0xFFFF0000u), acc.y);
    acc.z = fmaf(x0, bfbits(q0.y << 16), acc.z);
    acc.w = fmaf(x0, bfbits(q0.y & 0xFFFF0000u), acc.w);
    acc.x = fmaf(x1, bfbits(q1.x << 16), acc.x);
    acc.y = fmaf(x1, bfbits(q1.x & 0xFFFF0000u), acc.y);
    acc.z = fmaf(x1, bfbits(q1.y << 16), acc.z);
    acc.w = fmaf(x1, bfbits(q1.y & 0xFFFF0000u), acc.w);
    acc.x = fmaf(x2, bfbits(q2.x << 16), acc.x);
    acc.y = fmaf(x2, bfbits(q2.x & 0xFFFF0000u), acc.y);
    acc.z = fmaf(x2, bfbits(q2.y << 16), acc.z);
    acc.w = fmaf(x2, bfbits(q2.y & 0xFFFF0000u), acc.w);
    acc.x = fmaf(x3, bfbits(q3.x << 16), acc.x);
    acc.y = fmaf(x3, bfbits(q3.x & 0xFFFF0000u), acc.y);
    acc.z = fmaf(x3, bfbits(q3.y << 16), acc.z);
    acc.w = fmaf(x3, bfbits(q3.y & 0xFFFF0000u), acc.w);
  }
  for (; j < end; ++j) {
    int s0 = srcp[j];
    float2 l0 = *(const float2*)&el[(size_t)s0 * 2];
    uint2 q0 = *(const uint2*)&featb[(size_t)s0 * 256 + lane * 4];
    float e0 = (h0 ? l0.x : l0.y) + er_m;
    e0 = fminf((e0 >= 0.f) ? e0 : NEG_SLOPE * e0, 60.f);
    float x0 = __expf(e0);
    den += x0;
    acc.x = fmaf(x0, bfbits(q0.x << 16), acc.x);
    acc.y = fmaf(x0, bfbits(q0.x & 0xFFFF0000u), acc.y);
    acc.z = fmaf(x0, bfbits(q0.y << 16), acc.z);
    acc.w = fmaf(x0, bfbits(q0.y & 0xFFFF0000u), acc.w);
  }

  float4 b4 = *(const float4*)&b[lane * 4];
  float4 o;
  if (end > beg) {
    float inv = 1.0f / den;
    o.x = fmaf(acc.x, inv, b4.x);
    o.y = fmaf(acc.y, inv, b4.y);
    o.z = fmaf(acc.z, inv, b4.z);
    o.w = fmaf(acc.w, inv, b4.w);
  } else {
    o = b4;
  }
  if (out) *(float4*)&out[(size_t)node * 256 + lane * 4] = o;
  if (hnext) {
    float px = __shfl_xor(o.x, 32);
    float py = __shfl_xor(o.y, 32);
    float pz = __shfl_xor(o.z, 32);
    float pw = __shfl_xor(o.w, 32);
    if (lane < 32) {
      float4 hn = make_float4((o.x + px) * 0.5f, (o.y + py) * 0.5f,
                              (o.z + pz) * 0.5f, (o.w + pw) * 0.5f);
      *(float4*)&hnext[(size_t)node * 128 + lane * 4] = hn;
    }
  }
}

// ---------------- launch ----------------

extern "C" void kernel_launch(void* const* d_in, const int* in_sizes, int n_in,
                              void* d_out, int out_size, void* d_ws, size_t ws_size,
                              hipStream_t stream) {
  const float* x   = (const float*)d_in[0];
  const float* Ws  = (const float*)d_in[1];
  const float* als = (const float*)d_in[2];
  const float* ars = (const float*)d_in[3];
  const float* bs  = (const float*)d_in[4];
  const int*   src = (const int*)d_in[5];
  const int*   dst = (const int*)d_in[6];
  const int N = in_sizes[0] / 128;   // 50000
  const int E = in_sizes[5];         // 800000
  float* out = (float*)d_out;

  char* ws = (char*)d_ws;
  auto alloc = [&](size_t bytes) {
    char* p = ws;
    ws += (bytes + 255) & ~(size_t)255;
    return p;
  };
  unsigned short* featb = (unsigned short*)alloc((size_t)N * 256 * 2);
  float* hbuf    = (float*)alloc((size_t)N * 128 * 4);
  int*   srcp    = (int*)alloc((size_t)E * 4);
  int*   offsets = (int*)alloc((size_t)(N + 1) * 4);
  int*   cursor  = (int*)alloc((size_t)N * 4);
  int*   counts  = (int*)alloc((size_t)N * 4);
  float* el      = (float*)alloc((size_t)N * 2 * 4);
  float* er      = (float*)alloc((size_t)N * 2 * 4);
  int*   blocksum = (int*)alloc((size_t)256 * 4);
  int*   blockoff = (int*)alloc((size_t)256 * 4);
  unsigned short* Whi = (unsigned short*)alloc((size_t)65536 * 2);
  unsigned short* Wlo = (unsigned short*)alloc((size_t)65536 * 2);

  const int nb = (N + 1023) / 1024;  // 49

  // CSR by dst (dst invariant across layers: build once)
  hipMemsetAsync(counts, 0, (size_t)N * 4, stream);
  hist_kernel<<<dim3((E + 255) / 256), dim3(256), 0, stream>>>(dst, counts, E);
  scan1_kernel<<<dim3(nb), dim3(256), 0, stream>>>(counts, blocksum, N);
  scan2_kernel<<<dim3(1), dim3(256), 0, stream>>>(blocksum, blockoff, nb, offsets, N);
  scan3_kernel<<<dim3(nb), dim3(256), 0, stream>>>(counts, blockoff, offsets, cursor, N);
  scatter_kernel<<<dim3((E + 255) / 256), dim3(256), 0, stream>>>(src, dst, cursor, srcp, E);

  // pack W (both layers) into MFMA B-fragment order, bf16 hi/lo
  wpack_kernel<<<dim3(32), dim3(256), 0, stream>>>(Ws, Whi, Wlo);

  for (int l = 0; l < 2; ++l) {
    const float* hin = (l == 0) ? x : hbuf;
    const float* al  = als + (size_t)l * 256;
    const float* ar  = ars + (size_t)l * 256;
    const float* b   = bs  + (size_t)l * 256;
    gemm_feat_kernel<<<dim3((N + 63) / 64), dim3(256), 0, stream>>>(
        hin, Whi + (size_t)l * 32768, Wlo + (size_t)l * 32768,
        al, ar, featb, el, er, N);
    aggregate_kernel<<<dim3((N + 3) / 4), dim3(256), 0, stream>>>(
        featb, el, er, srcp, offsets, b,
        (l == 1) ? out : nullptr,
        (l == 0) ? hbuf : nullptr, N);
  }
}